// Round 1
// baseline (1807.365 us; speedup 1.0000x reference)
//
#include <hip/hip_runtime.h>
#include <cstddef>

// Problem constants (match reference)
#define D_FEAT 64
#define S_DIM 16
#define H_DIM 32
#define OUT_DIM 16
#define MAX_IT 5

__device__ __forceinline__ float fast_tanh(float x) {
    // tanh(x) = (e^{2x}-1)/(e^{2x}+1), clamped to avoid inf/inf
    float xc = fminf(fmaxf(x, -15.0f), 15.0f);
    float e = __expf(2.0f * xc);
    return (e - 1.0f) / (e + 1.0f);
}

// pre[j][e] = bst1[j] + sum_k feat[e][k] * Wst1[k][j]   (k < 64), stored transposed [32][E]
__global__ __launch_bounds__(256)
void gnn_pre(const float* __restrict__ feat, const float* __restrict__ Wst1,
             const float* __restrict__ bst1, float* __restrict__ preT, int E) {
    int e = blockIdx.x * 256 + threadIdx.x;
    if (e >= E) return;
    float acc[H_DIM];
#pragma unroll
    for (int j = 0; j < H_DIM; ++j) acc[j] = bst1[j];
    const float4* f4 = reinterpret_cast<const float4*>(feat + (size_t)e * D_FEAT);
#pragma unroll 4
    for (int k4 = 0; k4 < D_FEAT / 4; ++k4) {
        float4 v = f4[k4];
        const float* w = Wst1 + k4 * 4 * H_DIM;
#pragma unroll
        for (int j = 0; j < H_DIM; ++j) acc[j] = fmaf(v.x, w[j], acc[j]);
#pragma unroll
        for (int j = 0; j < H_DIM; ++j) acc[j] = fmaf(v.y, w[H_DIM + j], acc[j]);
#pragma unroll
        for (int j = 0; j < H_DIM; ++j) acc[j] = fmaf(v.z, w[2 * H_DIM + j], acc[j]);
#pragma unroll
        for (int j = 0; j < H_DIM; ++j) acc[j] = fmaf(v.w, w[3 * H_DIM + j], acc[j]);
    }
#pragma unroll
    for (int j = 0; j < H_DIM; ++j) preT[(size_t)j * E + e] = acc[j];
}

// One iteration's edge phase: res = tanh(tanh(pre + state[dst]@Wst1[64:]) @ Wst2 + bst2)
// scatter-add into new_state[src]
__global__ __launch_bounds__(256)
void gnn_edge(const float* __restrict__ preT, const float* __restrict__ Wst1,
              const float* __restrict__ Wst2, const float* __restrict__ bst2,
              const int* __restrict__ src, const int* __restrict__ dst,
              const float* __restrict__ state, float* __restrict__ new_state,
              const int* __restrict__ flags, int E) {
    if (flags[0]) return;  // converged earlier -> frozen, no more work
    int e = blockIdx.x * 256 + threadIdx.x;
    if (e >= E) return;
    int d = dst[e];
    int s = src[e];

    float st[S_DIM];
    const float4* sp = reinterpret_cast<const float4*>(state + (size_t)d * S_DIM);
    float4 v0 = sp[0], v1 = sp[1], v2 = sp[2], v3 = sp[3];
    st[0] = v0.x; st[1] = v0.y; st[2] = v0.z; st[3] = v0.w;
    st[4] = v1.x; st[5] = v1.y; st[6] = v1.z; st[7] = v1.w;
    st[8] = v2.x; st[9] = v2.y; st[10] = v2.z; st[11] = v2.w;
    st[12] = v3.x; st[13] = v3.y; st[14] = v3.z; st[15] = v3.w;

    float h[H_DIM];
#pragma unroll
    for (int j = 0; j < H_DIM; ++j) h[j] = preT[(size_t)j * E + e];
#pragma unroll
    for (int k = 0; k < S_DIM; ++k) {
        const float* w = Wst1 + (size_t)(D_FEAT + k) * H_DIM;
        float sk = st[k];
#pragma unroll
        for (int j = 0; j < H_DIM; ++j) h[j] = fmaf(sk, w[j], h[j]);
    }
#pragma unroll
    for (int j = 0; j < H_DIM; ++j) h[j] = fast_tanh(h[j]);

    float r[S_DIM];
#pragma unroll
    for (int i = 0; i < S_DIM; ++i) r[i] = bst2[i];
#pragma unroll
    for (int j = 0; j < H_DIM; ++j) {
        float hj = h[j];
        const float* w = Wst2 + (size_t)j * S_DIM;
#pragma unroll
        for (int i = 0; i < S_DIM; ++i) r[i] = fmaf(hj, w[i], r[i]);
    }

    float* ns = new_state + (size_t)s * S_DIM;
#pragma unroll
    for (int i = 0; i < S_DIM; ++i) atomicAdd(ns + i, fast_tanh(r[i]));
}

// Per-node: convergence distance, copy new_state -> state, zero new_state for next iter
__global__ __launch_bounds__(256)
void gnn_node(float* __restrict__ state, float* __restrict__ new_state,
              int* __restrict__ flags, int N) {
    if (flags[0]) return;
    int n = blockIdx.x * 256 + threadIdx.x;
    if (n >= N) return;
    float4* sp = reinterpret_cast<float4*>(state + (size_t)n * S_DIM);
    float4* np_ = reinterpret_cast<float4*>(new_state + (size_t)n * S_DIM);
    float d2 = 0.0f;
    float4 z = make_float4(0.f, 0.f, 0.f, 0.f);
#pragma unroll
    for (int q = 0; q < 4; ++q) {
        float4 nv = np_[q];
        float4 ov = sp[q];
        float dx = nv.x - ov.x, dy = nv.y - ov.y, dz = nv.z - ov.z, dw = nv.w - ov.w;
        d2 += dx * dx + dy * dy + dz * dz + dw * dw;
        sp[q] = nv;
        np_[q] = z;
    }
    // converged iff sqrt(d2 + 1e-10) <= 0.01  <=>  d2 + 1e-10 <= 1e-4
    if (d2 + 1e-10f > 1e-4f) flags[1] = 1;  // violation: not converged
}

__global__ void gnn_flag(int* flags) {
    if (flags[1] == 0) flags[0] = 1;  // all nodes converged -> done |= true
    flags[1] = 0;
}

// Output MLP + softmax
__global__ __launch_bounds__(256)
void gnn_out(const float* __restrict__ state, const float* __restrict__ Wout1,
             const float* __restrict__ bout1, const float* __restrict__ Wout2,
             const float* __restrict__ bout2, float* __restrict__ out, int N) {
    int n = blockIdx.x * 256 + threadIdx.x;
    if (n >= N) return;
    float st[S_DIM];
    const float4* sp = reinterpret_cast<const float4*>(state + (size_t)n * S_DIM);
    float4 v0 = sp[0], v1 = sp[1], v2 = sp[2], v3 = sp[3];
    st[0] = v0.x; st[1] = v0.y; st[2] = v0.z; st[3] = v0.w;
    st[4] = v1.x; st[5] = v1.y; st[6] = v1.z; st[7] = v1.w;
    st[8] = v2.x; st[9] = v2.y; st[10] = v2.z; st[11] = v2.w;
    st[12] = v3.x; st[13] = v3.y; st[14] = v3.z; st[15] = v3.w;

    float h[H_DIM];
#pragma unroll
    for (int j = 0; j < H_DIM; ++j) {
        float acc = bout1[j];
#pragma unroll
        for (int k = 0; k < S_DIM; ++k) acc = fmaf(st[k], Wout1[(size_t)k * H_DIM + j], acc);
        h[j] = fast_tanh(acc);
    }
    float l[OUT_DIM];
#pragma unroll
    for (int i = 0; i < OUT_DIM; ++i) l[i] = bout2[i];
#pragma unroll
    for (int j = 0; j < H_DIM; ++j) {
        float hj = h[j];
#pragma unroll
        for (int i = 0; i < OUT_DIM; ++i) l[i] = fmaf(hj, Wout2[(size_t)j * OUT_DIM + i], l[i]);
    }
    float m = l[0];
#pragma unroll
    for (int i = 1; i < OUT_DIM; ++i) m = fmaxf(m, l[i]);
    float sum = 0.0f;
#pragma unroll
    for (int i = 0; i < OUT_DIM; ++i) {
        float t = __expf(l[i] - m);
        l[i] = t;
        sum += t;
    }
    float inv = 1.0f / sum;
    float4* op = reinterpret_cast<float4*>(out + (size_t)n * OUT_DIM);
    op[0] = make_float4(l[0] * inv, l[1] * inv, l[2] * inv, l[3] * inv);
    op[1] = make_float4(l[4] * inv, l[5] * inv, l[6] * inv, l[7] * inv);
    op[2] = make_float4(l[8] * inv, l[9] * inv, l[10] * inv, l[11] * inv);
    op[3] = make_float4(l[12] * inv, l[13] * inv, l[14] * inv, l[15] * inv);
}

extern "C" void kernel_launch(void* const* d_in, const int* in_sizes, int n_in,
                              void* d_out, int out_size, void* d_ws, size_t ws_size,
                              hipStream_t stream) {
    const float* edge_feat = (const float*)d_in[0];
    const float* Wst1 = (const float*)d_in[1];
    const float* bst1 = (const float*)d_in[2];
    const float* Wst2 = (const float*)d_in[3];
    const float* bst2 = (const float*)d_in[4];
    const float* Wout1 = (const float*)d_in[5];
    const float* bout1 = (const float*)d_in[6];
    const float* Wout2 = (const float*)d_in[7];
    const float* bout2 = (const float*)d_in[8];
    const int* esrc = (const int*)d_in[9];
    const int* edst = (const int*)d_in[10];
    const int E = in_sizes[9];
    const int N = out_size / OUT_DIM;
    float* out = (float*)d_out;

    // Workspace layout: state[N*16] | new_state[N*16] | preT[32*E] | flags[2]
    float* state = (float*)d_ws;
    float* new_state = state + (size_t)N * S_DIM;
    float* preT = new_state + (size_t)N * S_DIM;
    int* flags = (int*)(preT + (size_t)H_DIM * E);

    hipMemsetAsync(state, 0, (size_t)N * S_DIM * 2 * sizeof(float), stream);
    hipMemsetAsync(flags, 0, 2 * sizeof(int), stream);

    int ebl = (E + 255) / 256;
    int nbl = (N + 255) / 256;

    gnn_pre<<<ebl, 256, 0, stream>>>(edge_feat, Wst1, bst1, preT, E);
    for (int it = 0; it < MAX_IT; ++it) {
        gnn_edge<<<ebl, 256, 0, stream>>>(preT, Wst1, Wst2, bst2, esrc, edst,
                                          state, new_state, flags, E);
        gnn_node<<<nbl, 256, 0, stream>>>(state, new_state, flags, N);
        gnn_flag<<<1, 1, 0, stream>>>(flags);
    }
    gnn_out<<<nbl, 256, 0, stream>>>(state, Wout1, bout1, Wout2, bout2, out, N);
}

// Round 2
// 422.821 us; speedup vs baseline: 4.2745x; 4.2745x over previous
//
#include <hip/hip_runtime.h>
#include <cstddef>

#define D_FEAT 64
#define S_DIM 16
#define H_DIM 32
#define OUT_DIM 16
#define MAX_IT 5

__device__ __forceinline__ float fast_tanh(float x) {
    float xc = fminf(fmaxf(x, -15.0f), 15.0f);
    float e = __expf(2.0f * xc);
    return (e - 1.0f) / (e + 1.0f);
}

// ---- CSR construction (counting sort by src) ----
__global__ __launch_bounds__(256)
void k_hist(const int* __restrict__ src, int* __restrict__ deg, int E) {
    int e = blockIdx.x * 256 + threadIdx.x;
    if (e < E) atomicAdd(&deg[src[e]], 1);
}

// single-block exclusive scan (shuffle-based, 1024 threads)
__global__ __launch_bounds__(1024)
void k_scan(const int* __restrict__ deg, int* __restrict__ rowptr,
            int* __restrict__ cursor, int N) {
    __shared__ int wsum[16];
    __shared__ int carry;
    int lane = threadIdx.x & 63;
    int wid = threadIdx.x >> 6;
    if (threadIdx.x == 0) carry = 0;
    __syncthreads();
    for (int base = 0; base < N; base += 1024) {
        int i = base + (int)threadIdx.x;
        int v = (i < N) ? deg[i] : 0;
        int incl = v;
#pragma unroll
        for (int off = 1; off < 64; off <<= 1) {
            int t = __shfl_up(incl, off, 64);
            if (lane >= off) incl += t;
        }
        if (lane == 63) wsum[wid] = incl;
        __syncthreads();
        if (wid == 0) {
            int w = (lane < 16) ? wsum[lane] : 0;
            int wi = w;
#pragma unroll
            for (int off = 1; off < 16; off <<= 1) {
                int t = __shfl_up(wi, off, 64);
                if (lane >= off) wi += t;
            }
            if (lane < 16) wsum[lane] = wi - w;  // exclusive wave offset
        }
        __syncthreads();
        int excl = incl - v + wsum[wid] + carry;
        if (i < N) { rowptr[i] = excl; cursor[i] = excl; }
        __syncthreads();
        if ((int)threadIdx.x == 1023) carry = excl + v;  // = old carry + tile total
        __syncthreads();
    }
    if (threadIdx.x == 0) rowptr[N] = carry;
}

__global__ __launch_bounds__(256)
void k_scatter(const int* __restrict__ src, const int* __restrict__ dst,
               int* __restrict__ cursor, int* __restrict__ perm,
               int* __restrict__ dstp, int E) {
    int e = blockIdx.x * 256 + threadIdx.x;
    if (e >= E) return;
    int s = src[e];
    int pos = atomicAdd(&cursor[s], 1);
    perm[pos] = e;
    dstp[pos] = dst[e];
}

// pre[ep][j] = bst1[j] + feat[perm[ep]] @ Wst1[:64]  (stored in sorted edge order)
__global__ __launch_bounds__(256)
void k_pre(const float* __restrict__ feat, const float* __restrict__ Wst1,
           const float* __restrict__ bst1, const int* __restrict__ perm,
           float* __restrict__ pre, int E) {
    int ep = blockIdx.x * 256 + threadIdx.x;
    if (ep >= E) return;
    int e = perm[ep];
    float acc[H_DIM];
#pragma unroll
    for (int j = 0; j < H_DIM; ++j) acc[j] = bst1[j];
    const float4* f4 = reinterpret_cast<const float4*>(feat + (size_t)e * D_FEAT);
#pragma unroll 4
    for (int k4 = 0; k4 < D_FEAT / 4; ++k4) {
        float4 v = f4[k4];
        const float* w = Wst1 + k4 * 4 * H_DIM;
#pragma unroll
        for (int j = 0; j < H_DIM; ++j) acc[j] = fmaf(v.x, w[j], acc[j]);
#pragma unroll
        for (int j = 0; j < H_DIM; ++j) acc[j] = fmaf(v.y, w[H_DIM + j], acc[j]);
#pragma unroll
        for (int j = 0; j < H_DIM; ++j) acc[j] = fmaf(v.z, w[2 * H_DIM + j], acc[j]);
#pragma unroll
        for (int j = 0; j < H_DIM; ++j) acc[j] = fmaf(v.w, w[3 * H_DIM + j], acc[j]);
    }
    float4* op = reinterpret_cast<float4*>(pre + (size_t)ep * H_DIM);
#pragma unroll
    for (int j4 = 0; j4 < 8; ++j4)
        op[j4] = make_float4(acc[j4 * 4], acc[j4 * 4 + 1], acc[j4 * 4 + 2], acc[j4 * 4 + 3]);
}

// res[ep] = tanh(tanh(pre[ep] + nodeH[dstp[ep]]) @ Wst2 + bst2)
__global__ __launch_bounds__(256)
void gnn_edge(const float* __restrict__ pre, const float* __restrict__ nodeH,
              const int* __restrict__ dstp, const float* __restrict__ Wst2,
              const float* __restrict__ bst2, float* __restrict__ res,
              const int* __restrict__ flags, int E) {
    if (flags[0]) return;
    int ep = blockIdx.x * 256 + threadIdx.x;
    if (ep >= E) return;
    int d = dstp[ep];
    const float4* pp = reinterpret_cast<const float4*>(pre + (size_t)ep * H_DIM);
    const float4* hp = reinterpret_cast<const float4*>(nodeH + (size_t)d * H_DIM);
    float h[H_DIM];
#pragma unroll
    for (int j4 = 0; j4 < 8; ++j4) {
        float4 a = pp[j4], b = hp[j4];
        h[j4 * 4 + 0] = fast_tanh(a.x + b.x);
        h[j4 * 4 + 1] = fast_tanh(a.y + b.y);
        h[j4 * 4 + 2] = fast_tanh(a.z + b.z);
        h[j4 * 4 + 3] = fast_tanh(a.w + b.w);
    }
    float r[S_DIM];
#pragma unroll
    for (int i = 0; i < S_DIM; ++i) r[i] = bst2[i];
#pragma unroll
    for (int j = 0; j < H_DIM; ++j) {
        const float* w = Wst2 + (size_t)j * S_DIM;
        float hj = h[j];
#pragma unroll
        for (int i = 0; i < S_DIM; ++i) r[i] = fmaf(hj, w[i], r[i]);
    }
    float4* op = reinterpret_cast<float4*>(res + (size_t)ep * S_DIM);
    op[0] = make_float4(fast_tanh(r[0]), fast_tanh(r[1]), fast_tanh(r[2]), fast_tanh(r[3]));
    op[1] = make_float4(fast_tanh(r[4]), fast_tanh(r[5]), fast_tanh(r[6]), fast_tanh(r[7]));
    op[2] = make_float4(fast_tanh(r[8]), fast_tanh(r[9]), fast_tanh(r[10]), fast_tanh(r[11]));
    op[3] = make_float4(fast_tanh(r[12]), fast_tanh(r[13]), fast_tanh(r[14]), fast_tanh(r[15]));
}

// 4 threads per node: segment-sum res, convergence check, state update, next nodeH
__global__ __launch_bounds__(256)
void k_reduce(const float* __restrict__ res, const int* __restrict__ rowptr,
              float* __restrict__ state, float* __restrict__ nodeH,
              const float* __restrict__ Wst1, int* __restrict__ flags, int N) {
    if (flags[0]) return;
    int t = blockIdx.x * 256 + threadIdx.x;
    int n = t >> 2;
    int q = t & 3;
    if (n >= N) return;
    int r0 = rowptr[n], r1 = rowptr[n + 1];
    const float4* rp = reinterpret_cast<const float4*>(res);
    float4 acc = make_float4(0.f, 0.f, 0.f, 0.f);
    for (int e = r0; e < r1; ++e) {
        float4 v = rp[(size_t)e * 4 + q];
        acc.x += v.x; acc.y += v.y; acc.z += v.z; acc.w += v.w;
    }
    float4* sp = reinterpret_cast<float4*>(state + (size_t)n * S_DIM);
    float4 old = sp[q];
    float dx = acc.x - old.x, dy = acc.y - old.y, dz = acc.z - old.z, dw = acc.w - old.w;
    float d2 = dx * dx + dy * dy + dz * dz + dw * dw;
    sp[q] = acc;
    d2 += __shfl_xor(d2, 1);
    d2 += __shfl_xor(d2, 2);
    if (q == 0 && d2 + 1e-10f > 1e-4f) flags[1] = 1;  // not converged

    // gather full 16-dim state within the 4-lane group
    float st[S_DIM];
    st[q * 4 + 0] = acc.x; st[q * 4 + 1] = acc.y; st[q * 4 + 2] = acc.z; st[q * 4 + 3] = acc.w;
#pragma unroll
    for (int m = 1; m < 4; ++m) {
        int qs = q ^ m;
        st[qs * 4 + 0] = __shfl_xor(acc.x, m);
        st[qs * 4 + 1] = __shfl_xor(acc.y, m);
        st[qs * 4 + 2] = __shfl_xor(acc.z, m);
        st[qs * 4 + 3] = __shfl_xor(acc.w, m);
    }
    // nodeH[n][q*8 .. q*8+8) = state @ Wst1[64:]
    float hh[8];
#pragma unroll
    for (int j = 0; j < 8; ++j) hh[j] = 0.f;
#pragma unroll
    for (int k = 0; k < S_DIM; ++k) {
        const float* w = Wst1 + (size_t)(D_FEAT + k) * H_DIM + q * 8;
        float sk = st[k];
#pragma unroll
        for (int j = 0; j < 8; ++j) hh[j] = fmaf(sk, w[j], hh[j]);
    }
    float4* hp = reinterpret_cast<float4*>(nodeH + (size_t)n * H_DIM + q * 8);
    hp[0] = make_float4(hh[0], hh[1], hh[2], hh[3]);
    hp[1] = make_float4(hh[4], hh[5], hh[6], hh[7]);
}

__global__ void gnn_flag(int* flags) {
    if (flags[1] == 0) flags[0] = 1;
    flags[1] = 0;
}

__global__ __launch_bounds__(256)
void gnn_out(const float* __restrict__ state, const float* __restrict__ Wout1,
             const float* __restrict__ bout1, const float* __restrict__ Wout2,
             const float* __restrict__ bout2, float* __restrict__ out, int N) {
    int n = blockIdx.x * 256 + threadIdx.x;
    if (n >= N) return;
    float st[S_DIM];
    const float4* sp = reinterpret_cast<const float4*>(state + (size_t)n * S_DIM);
    float4 v0 = sp[0], v1 = sp[1], v2 = sp[2], v3 = sp[3];
    st[0] = v0.x; st[1] = v0.y; st[2] = v0.z; st[3] = v0.w;
    st[4] = v1.x; st[5] = v1.y; st[6] = v1.z; st[7] = v1.w;
    st[8] = v2.x; st[9] = v2.y; st[10] = v2.z; st[11] = v2.w;
    st[12] = v3.x; st[13] = v3.y; st[14] = v3.z; st[15] = v3.w;

    float h[H_DIM];
#pragma unroll
    for (int j = 0; j < H_DIM; ++j) {
        float acc = bout1[j];
#pragma unroll
        for (int k = 0; k < S_DIM; ++k) acc = fmaf(st[k], Wout1[(size_t)k * H_DIM + j], acc);
        h[j] = fast_tanh(acc);
    }
    float l[OUT_DIM];
#pragma unroll
    for (int i = 0; i < OUT_DIM; ++i) l[i] = bout2[i];
#pragma unroll
    for (int j = 0; j < H_DIM; ++j) {
        float hj = h[j];
#pragma unroll
        for (int i = 0; i < OUT_DIM; ++i) l[i] = fmaf(hj, Wout2[(size_t)j * OUT_DIM + i], l[i]);
    }
    float m = l[0];
#pragma unroll
    for (int i = 1; i < OUT_DIM; ++i) m = fmaxf(m, l[i]);
    float sum = 0.0f;
#pragma unroll
    for (int i = 0; i < OUT_DIM; ++i) {
        float t = __expf(l[i] - m);
        l[i] = t;
        sum += t;
    }
    float inv = 1.0f / sum;
    float4* op = reinterpret_cast<float4*>(out + (size_t)n * OUT_DIM);
    op[0] = make_float4(l[0] * inv, l[1] * inv, l[2] * inv, l[3] * inv);
    op[1] = make_float4(l[4] * inv, l[5] * inv, l[6] * inv, l[7] * inv);
    op[2] = make_float4(l[8] * inv, l[9] * inv, l[10] * inv, l[11] * inv);
    op[3] = make_float4(l[12] * inv, l[13] * inv, l[14] * inv, l[15] * inv);
}

extern "C" void kernel_launch(void* const* d_in, const int* in_sizes, int n_in,
                              void* d_out, int out_size, void* d_ws, size_t ws_size,
                              hipStream_t stream) {
    const float* edge_feat = (const float*)d_in[0];
    const float* Wst1 = (const float*)d_in[1];
    const float* bst1 = (const float*)d_in[2];
    const float* Wst2 = (const float*)d_in[3];
    const float* bst2 = (const float*)d_in[4];
    const float* Wout1 = (const float*)d_in[5];
    const float* bout1 = (const float*)d_in[6];
    const float* Wout2 = (const float*)d_in[7];
    const float* bout2 = (const float*)d_in[8];
    const int* esrc = (const int*)d_in[9];
    const int* edst = (const int*)d_in[10];
    const int E = in_sizes[9];
    const int N = out_size / OUT_DIM;
    float* out = (float*)d_out;

    // ws layout: state[N*16] | nodeH[N*32] | pre[E*32] | res[E*16] |
    //            perm[E] | dstp[E] | rowptr[N+1] | cursor[N] | deg[N] | flags[2]
    float* state = (float*)d_ws;
    float* nodeH = state + (size_t)N * S_DIM;
    float* pre = nodeH + (size_t)N * H_DIM;
    float* res = pre + (size_t)E * H_DIM;
    int* perm = (int*)(res + (size_t)E * S_DIM);
    int* dstp = perm + E;
    int* rowptr = dstp + E;
    int* cursor = rowptr + (N + 1);
    int* deg = cursor + N;
    int* flags = deg + N;

    hipMemsetAsync(state, 0, (size_t)N * S_DIM * sizeof(float), stream);
    hipMemsetAsync(nodeH, 0, (size_t)N * H_DIM * sizeof(float), stream);  // state0=0 -> nodeH0=0
    hipMemsetAsync(deg, 0, (size_t)N * sizeof(int), stream);
    hipMemsetAsync(flags, 0, 2 * sizeof(int), stream);

    int ebl = (E + 255) / 256;
    int nbl = (N + 255) / 256;
    int rbl = (N * 4 + 255) / 256;

    k_hist<<<ebl, 256, 0, stream>>>(esrc, deg, E);
    k_scan<<<1, 1024, 0, stream>>>(deg, rowptr, cursor, N);
    k_scatter<<<ebl, 256, 0, stream>>>(esrc, edst, cursor, perm, dstp, E);
    k_pre<<<ebl, 256, 0, stream>>>(edge_feat, Wst1, bst1, perm, pre, E);

    for (int it = 0; it < MAX_IT; ++it) {
        gnn_edge<<<ebl, 256, 0, stream>>>(pre, nodeH, dstp, Wst2, bst2, res, flags, E);
        k_reduce<<<rbl, 256, 0, stream>>>(res, rowptr, state, nodeH, Wst1, flags, N);
        gnn_flag<<<1, 1, 0, stream>>>(flags);
    }
    gnn_out<<<nbl, 256, 0, stream>>>(state, Wout1, bout1, Wout2, bout2, out, N);
}

// Round 3
// 333.459 us; speedup vs baseline: 5.4200x; 1.2680x over previous
//
#include <hip/hip_runtime.h>
#include <cstddef>

#define D_FEAT 64
#define S_DIM 16
#define H_DIM 32
#define OUT_DIM 16
#define MAX_IT 5

typedef _Float16 half8 __attribute__((ext_vector_type(8)));

__device__ __forceinline__ float fast_tanh(float x) {
    float xc = fminf(fmaxf(x, -15.0f), 15.0f);
    float e = __expf(2.0f * xc);
    return (e - 1.0f) / (e + 1.0f);
}

// ---- CSR construction (counting sort by src) ----
__global__ __launch_bounds__(256)
void k_hist(const int* __restrict__ src, int* __restrict__ deg, int E) {
    int e = blockIdx.x * 256 + threadIdx.x;
    if (e < E) atomicAdd(&deg[src[e]], 1);
}

// single-block exclusive scan -> cursor
__global__ __launch_bounds__(1024)
void k_scan(const int* __restrict__ deg, int* __restrict__ cursor, int N) {
    __shared__ int wsum[16];
    __shared__ int carry;
    int lane = threadIdx.x & 63;
    int wid = threadIdx.x >> 6;
    if (threadIdx.x == 0) carry = 0;
    __syncthreads();
    for (int base = 0; base < N; base += 1024) {
        int i = base + (int)threadIdx.x;
        int v = (i < N) ? deg[i] : 0;
        int incl = v;
#pragma unroll
        for (int off = 1; off < 64; off <<= 1) {
            int t = __shfl_up(incl, off, 64);
            if (lane >= off) incl += t;
        }
        if (lane == 63) wsum[wid] = incl;
        __syncthreads();
        if (wid == 0) {
            int w = (lane < 16) ? wsum[lane] : 0;
            int wi = w;
#pragma unroll
            for (int off = 1; off < 16; off <<= 1) {
                int t = __shfl_up(wi, off, 64);
                if (lane >= off) wi += t;
            }
            if (lane < 16) wsum[lane] = wi - w;
        }
        __syncthreads();
        int excl = incl - v + wsum[wid] + carry;
        if (i < N) cursor[i] = excl;
        __syncthreads();
        if ((int)threadIdx.x == 1023) carry = excl + v;
        __syncthreads();
    }
}

// pos[e] = sorted position; dstp/srcp = dst/src in sorted order
__global__ __launch_bounds__(256)
void k_scatter(const int* __restrict__ src, const int* __restrict__ dst,
               int* __restrict__ cursor, int* __restrict__ pos,
               int* __restrict__ dstp, int* __restrict__ srcp, int E) {
    int e = blockIdx.x * 256 + threadIdx.x;
    if (e >= E) return;
    int s = src[e];
    int p = atomicAdd(&cursor[s], 1);
    pos[e] = p;
    dstp[p] = dst[e];
    srcp[p] = s;
}

// pre[pos[e]] = fp16(bst1 + feat[e] @ Wst1[:64]) — coalesced read, scattered 64B write
__global__ __launch_bounds__(256)
void k_pre(const float* __restrict__ feat, const float* __restrict__ Wst1,
           const float* __restrict__ bst1, const int* __restrict__ pos,
           _Float16* __restrict__ pre, int E) {
    int e = blockIdx.x * 256 + threadIdx.x;
    if (e >= E) return;
    float acc[H_DIM];
#pragma unroll
    for (int j = 0; j < H_DIM; ++j) acc[j] = bst1[j];
    const float4* f4 = reinterpret_cast<const float4*>(feat + (size_t)e * D_FEAT);
#pragma unroll 4
    for (int k4 = 0; k4 < D_FEAT / 4; ++k4) {
        float4 v = f4[k4];
        const float* w = Wst1 + k4 * 4 * H_DIM;
#pragma unroll
        for (int j = 0; j < H_DIM; ++j) acc[j] = fmaf(v.x, w[j], acc[j]);
#pragma unroll
        for (int j = 0; j < H_DIM; ++j) acc[j] = fmaf(v.y, w[H_DIM + j], acc[j]);
#pragma unroll
        for (int j = 0; j < H_DIM; ++j) acc[j] = fmaf(v.z, w[2 * H_DIM + j], acc[j]);
#pragma unroll
        for (int j = 0; j < H_DIM; ++j) acc[j] = fmaf(v.w, w[3 * H_DIM + j], acc[j]);
    }
    int p = pos[e];
    half8* op = reinterpret_cast<half8*>(pre + (size_t)p * H_DIM);
#pragma unroll
    for (int j8 = 0; j8 < 4; ++j8) {
        half8 v;
#pragma unroll
        for (int k = 0; k < 8; ++k) v[k] = (_Float16)acc[j8 * 8 + k];
        op[j8] = v;
    }
}

// Fused: edge MLP + in-block segmented sum + store/atomic into new_state
__global__ __launch_bounds__(256)
void k_edge(const _Float16* __restrict__ pre, const float* __restrict__ nodeH,
            const int* __restrict__ dstp, const int* __restrict__ srcp,
            const float* __restrict__ Wst2, const float* __restrict__ bst2,
            float* __restrict__ new_state, const int* __restrict__ flags, int E) {
    if (flags[0]) return;
    __shared__ float sres[256][20];  // stride 20 floats: 16B-aligned rows, staggered banks
    __shared__ int ssrc[256];
    int base = blockIdx.x * 256;
    int t = threadIdx.x;
    int ep = base + t;
    int s = (ep < E) ? srcp[ep] : (int)0x80000000;
    ssrc[t] = s;
    float res[S_DIM];
    if (ep < E) {
        int d = dstp[ep];
        const half8* pp = reinterpret_cast<const half8*>(pre + (size_t)ep * H_DIM);
        const float4* hp = reinterpret_cast<const float4*>(nodeH + (size_t)d * H_DIM);
        float h[H_DIM];
#pragma unroll
        for (int j8 = 0; j8 < 4; ++j8) {
            half8 pv = pp[j8];
            float4 a = hp[j8 * 2], b = hp[j8 * 2 + 1];
            h[j8 * 8 + 0] = fast_tanh((float)pv[0] + a.x);
            h[j8 * 8 + 1] = fast_tanh((float)pv[1] + a.y);
            h[j8 * 8 + 2] = fast_tanh((float)pv[2] + a.z);
            h[j8 * 8 + 3] = fast_tanh((float)pv[3] + a.w);
            h[j8 * 8 + 4] = fast_tanh((float)pv[4] + b.x);
            h[j8 * 8 + 5] = fast_tanh((float)pv[5] + b.y);
            h[j8 * 8 + 6] = fast_tanh((float)pv[6] + b.z);
            h[j8 * 8 + 7] = fast_tanh((float)pv[7] + b.w);
        }
        float r[S_DIM];
#pragma unroll
        for (int i = 0; i < S_DIM; ++i) r[i] = bst2[i];
#pragma unroll
        for (int j = 0; j < H_DIM; ++j) {
            const float* w = Wst2 + (size_t)j * S_DIM;
            float hj = h[j];
#pragma unroll
            for (int i = 0; i < S_DIM; ++i) r[i] = fmaf(hj, w[i], r[i]);
        }
#pragma unroll
        for (int i = 0; i < S_DIM; ++i) {
            res[i] = fast_tanh(r[i]);
            sres[t][i] = res[i];
        }
    }
    __syncthreads();
    if (ep >= E) return;
    bool local_head = (t == 0) || (ssrc[t - 1] != s);
    if (!local_head) return;
    float acc[S_DIM];
#pragma unroll
    for (int i = 0; i < S_DIM; ++i) acc[i] = res[i];
    int t2 = t + 1;
    while (t2 < 256 && base + t2 < E && ssrc[t2] == s) {
#pragma unroll
        for (int i = 0; i < S_DIM; ++i) acc[i] += sres[t2][i];
        ++t2;
    }
    bool trueStart = (t > 0) || (ep == 0) || (srcp[ep - 1] != s);
    int ge = base + t2;
    bool trueEnd = (t2 < 256) || (ge >= E) || (srcp[ge] != s);
    float* ns = new_state + (size_t)s * S_DIM;
    if (trueStart && trueEnd) {
        float4* nsp = reinterpret_cast<float4*>(ns);
        nsp[0] = make_float4(acc[0], acc[1], acc[2], acc[3]);
        nsp[1] = make_float4(acc[4], acc[5], acc[6], acc[7]);
        nsp[2] = make_float4(acc[8], acc[9], acc[10], acc[11]);
        nsp[3] = make_float4(acc[12], acc[13], acc[14], acc[15]);
    } else {
#pragma unroll
        for (int i = 0; i < S_DIM; ++i) atomicAdd(ns + i, acc[i]);
    }
}

// 4 threads/node: convergence, state <- new_state, new_state <- 0, nodeH = state@Wst1[64:]
__global__ __launch_bounds__(256)
void k_node(float* __restrict__ state, float* __restrict__ new_state,
            float* __restrict__ nodeH, const float* __restrict__ Wst1,
            int* __restrict__ flags, int N) {
    if (flags[0]) return;
    int tt = blockIdx.x * 256 + threadIdx.x;
    int n = tt >> 2;
    int q = tt & 3;
    if (n >= N) return;
    float4* nsp = reinterpret_cast<float4*>(new_state + (size_t)n * S_DIM);
    float4* sp = reinterpret_cast<float4*>(state + (size_t)n * S_DIM);
    float4 acc = nsp[q];
    float4 old = sp[q];
    float dx = acc.x - old.x, dy = acc.y - old.y, dz = acc.z - old.z, dw = acc.w - old.w;
    float d2 = dx * dx + dy * dy + dz * dz + dw * dw;
    sp[q] = acc;
    nsp[q] = make_float4(0.f, 0.f, 0.f, 0.f);
    d2 += __shfl_xor(d2, 1);
    d2 += __shfl_xor(d2, 2);
    if (q == 0 && d2 + 1e-10f > 1e-4f) flags[1] = 1;

    float st[S_DIM];
    st[q * 4 + 0] = acc.x; st[q * 4 + 1] = acc.y; st[q * 4 + 2] = acc.z; st[q * 4 + 3] = acc.w;
#pragma unroll
    for (int m = 1; m < 4; ++m) {
        int qs = q ^ m;
        st[qs * 4 + 0] = __shfl_xor(acc.x, m);
        st[qs * 4 + 1] = __shfl_xor(acc.y, m);
        st[qs * 4 + 2] = __shfl_xor(acc.z, m);
        st[qs * 4 + 3] = __shfl_xor(acc.w, m);
    }
    float hh[8];
#pragma unroll
    for (int j = 0; j < 8; ++j) hh[j] = 0.f;
#pragma unroll
    for (int k = 0; k < S_DIM; ++k) {
        const float* w = Wst1 + (size_t)(D_FEAT + k) * H_DIM + q * 8;
        float sk = st[k];
#pragma unroll
        for (int j = 0; j < 8; ++j) hh[j] = fmaf(sk, w[j], hh[j]);
    }
    float4* hp = reinterpret_cast<float4*>(nodeH + (size_t)n * H_DIM + q * 8);
    hp[0] = make_float4(hh[0], hh[1], hh[2], hh[3]);
    hp[1] = make_float4(hh[4], hh[5], hh[6], hh[7]);
}

__global__ void gnn_flag(int* flags) {
    if (flags[1] == 0) flags[0] = 1;
    flags[1] = 0;
}

__global__ __launch_bounds__(256)
void gnn_out(const float* __restrict__ state, const float* __restrict__ Wout1,
             const float* __restrict__ bout1, const float* __restrict__ Wout2,
             const float* __restrict__ bout2, float* __restrict__ out, int N) {
    int n = blockIdx.x * 256 + threadIdx.x;
    if (n >= N) return;
    float st[S_DIM];
    const float4* sp = reinterpret_cast<const float4*>(state + (size_t)n * S_DIM);
    float4 v0 = sp[0], v1 = sp[1], v2 = sp[2], v3 = sp[3];
    st[0] = v0.x; st[1] = v0.y; st[2] = v0.z; st[3] = v0.w;
    st[4] = v1.x; st[5] = v1.y; st[6] = v1.z; st[7] = v1.w;
    st[8] = v2.x; st[9] = v2.y; st[10] = v2.z; st[11] = v2.w;
    st[12] = v3.x; st[13] = v3.y; st[14] = v3.z; st[15] = v3.w;

    float h[H_DIM];
#pragma unroll
    for (int j = 0; j < H_DIM; ++j) {
        float acc = bout1[j];
#pragma unroll
        for (int k = 0; k < S_DIM; ++k) acc = fmaf(st[k], Wout1[(size_t)k * H_DIM + j], acc);
        h[j] = fast_tanh(acc);
    }
    float l[OUT_DIM];
#pragma unroll
    for (int i = 0; i < OUT_DIM; ++i) l[i] = bout2[i];
#pragma unroll
    for (int j = 0; j < H_DIM; ++j) {
        float hj = h[j];
#pragma unroll
        for (int i = 0; i < OUT_DIM; ++i) l[i] = fmaf(hj, Wout2[(size_t)j * OUT_DIM + i], l[i]);
    }
    float m = l[0];
#pragma unroll
    for (int i = 1; i < OUT_DIM; ++i) m = fmaxf(m, l[i]);
    float sum = 0.0f;
#pragma unroll
    for (int i = 0; i < OUT_DIM; ++i) {
        float tv = __expf(l[i] - m);
        l[i] = tv;
        sum += tv;
    }
    float inv = 1.0f / sum;
    float4* op = reinterpret_cast<float4*>(out + (size_t)n * OUT_DIM);
    op[0] = make_float4(l[0] * inv, l[1] * inv, l[2] * inv, l[3] * inv);
    op[1] = make_float4(l[4] * inv, l[5] * inv, l[6] * inv, l[7] * inv);
    op[2] = make_float4(l[8] * inv, l[9] * inv, l[10] * inv, l[11] * inv);
    op[3] = make_float4(l[12] * inv, l[13] * inv, l[14] * inv, l[15] * inv);
}

extern "C" void kernel_launch(void* const* d_in, const int* in_sizes, int n_in,
                              void* d_out, int out_size, void* d_ws, size_t ws_size,
                              hipStream_t stream) {
    const float* edge_feat = (const float*)d_in[0];
    const float* Wst1 = (const float*)d_in[1];
    const float* bst1 = (const float*)d_in[2];
    const float* Wst2 = (const float*)d_in[3];
    const float* bst2 = (const float*)d_in[4];
    const float* Wout1 = (const float*)d_in[5];
    const float* bout1 = (const float*)d_in[6];
    const float* Wout2 = (const float*)d_in[7];
    const float* bout2 = (const float*)d_in[8];
    const int* esrc = (const int*)d_in[9];
    const int* edst = (const int*)d_in[10];
    const int E = in_sizes[9];
    const int N = out_size / OUT_DIM;
    float* out = (float*)d_out;

    // ws layout (floats): state[N*16] | nodeH[N*32] | new_state[N*16] |
    // pre (_Float16, E*32) | pos[E] | dstp[E] | srcp[E] | deg[N] | cursor[N] | flags[2]
    float* state = (float*)d_ws;
    float* nodeH = state + (size_t)N * S_DIM;
    float* new_state = nodeH + (size_t)N * H_DIM;
    _Float16* pre = (_Float16*)(new_state + (size_t)N * S_DIM);
    int* pos = (int*)(pre + (size_t)E * H_DIM);
    int* dstp = pos + E;
    int* srcp = dstp + E;
    int* deg = srcp + E;
    int* cursor = deg + N;
    int* flags = cursor + N;

    hipMemsetAsync(state, 0, (size_t)N * (S_DIM + H_DIM + S_DIM) * sizeof(float), stream);
    hipMemsetAsync(deg, 0, (size_t)N * sizeof(int), stream);
    hipMemsetAsync(flags, 0, 2 * sizeof(int), stream);

    int ebl = (E + 255) / 256;
    int nbl = (N + 255) / 256;
    int rbl = (N * 4 + 255) / 256;

    k_hist<<<ebl, 256, 0, stream>>>(esrc, deg, E);
    k_scan<<<1, 1024, 0, stream>>>(deg, cursor, N);
    k_scatter<<<ebl, 256, 0, stream>>>(esrc, edst, cursor, pos, dstp, srcp, E);
    k_pre<<<ebl, 256, 0, stream>>>(edge_feat, Wst1, bst1, pos, pre, E);

    for (int it = 0; it < MAX_IT; ++it) {
        k_edge<<<ebl, 256, 0, stream>>>(pre, nodeH, dstp, srcp, Wst2, bst2,
                                        new_state, flags, E);
        k_node<<<rbl, 256, 0, stream>>>(state, new_state, nodeH, Wst1, flags, N);
        gnn_flag<<<1, 1, 0, stream>>>(flags);
    }
    gnn_out<<<nbl, 256, 0, stream>>>(state, Wout1, bout1, Wout2, bout2, out, N);
}